// Round 8
// baseline (843.118 us; speedup 1.0000x reference)
//
#include <hip/hip_runtime.h>

typedef unsigned short u16;
typedef unsigned int u32;
typedef _Float16 h4 __attribute__((ext_vector_type(4)));
typedef _Float16 h8 __attribute__((ext_vector_type(8)));
typedef float f32x4 __attribute__((ext_vector_type(4)));

#define MFMA16(a, b, c) __builtin_amdgcn_mfma_f32_16x16x32_f16((a), (b), (c), 0, 0, 0)
#define SW(t) ((((t) >> 2) & 3) << 5)   // x1 bank swizzle (32B granules, keyed by tok>>2)

__device__ __forceinline__ float wsum(float v) {
  #pragma unroll
  for (int o = 32; o > 0; o >>= 1) v += __shfl_down(v, o);
  return __shfl(v, 0);
}

// ---------- prep: qkv_w f32 [256k][768c] -> fp16 [row = h*96 + mat*32 + cc][256 k] ----------
__global__ void k_prep_qkv(const float* __restrict__ w, _Float16* __restrict__ o) {
  const int e = blockIdx.x * 256 + threadIdx.x;   // 768*256
  const int r = e >> 8, k = e & 255;
  const int h = r / 96, rem = r - h * 96;
  const int mat = rem >> 5, cc = rem & 31;
  o[e] = (_Float16)w[k * 768 + mat * 256 + h * 32 + cc];
}

// ---------- prep: proj_w f32 [256 in][256 out] -> fp16 [out][in] (k-contiguous) ----------
__global__ void k_prep_pw(const float* __restrict__ w, _Float16* __restrict__ o) {
  const int e = blockIdx.x * 256 + threadIdx.x;   // 256*256
  const int oc = e >> 8, ic = e & 255;
  o[e] = (_Float16)w[ic * 256 + oc];
}

// ---------- prep: fc1_w f32 [256k][1024c] -> fp16 [col][256 k] ----------
__global__ void k_prep_w1(const float* __restrict__ w, _Float16* __restrict__ o) {
  const int e = blockIdx.x * 256 + threadIdx.x;   // 1024*256
  const int col = e >> 8, k = e & 255;
  o[e] = (_Float16)w[k * 1024 + col];
}

// ---------- prep: fc2_w f32 [1024k][256c] -> fp16 [col][1024 k] ----------
__global__ void k_prep_w2(const float* __restrict__ w, _Float16* __restrict__ o) {
  const int e = blockIdx.x * 256 + threadIdx.x;   // 256*1024
  const int oc = e >> 10, k = e & 1023;
  o[e] = (_Float16)w[k * 256 + oc];
}

// ---------- prep: btab[h][e] = rtab[rpi[e]*8 + h]  (folds the indirection) ----------
__global__ void k_prep_btab(const int* __restrict__ rpi, const float* __restrict__ rtab,
                            float* __restrict__ btab) {
  const int e = blockIdx.x * 256 + threadIdx.x;
  if (e < 2401) {
    const int idx = rpi[e];
    #pragma unroll
    for (int h = 0; h < 8; ++h) btab[h * 2401 + e] = rtab[idx * 8 + h];
  }
}

// ---------- fused block kernel: attn (wave = head) + MLP, one window per block ----------
// 2048 blocks x 512 threads (8 waves), 128 KiB LDS (1 block/CU).
// Phase A (attention, verified structure):
//   ZN   [0,32768)   : LN1 out fp16 [64][512B], swz ((row&7)<<4); O overlays after barrier 2.
//   priv W=32768+w*12288: Q(4K)/K(4K)/V(4K); P overlays Q+K.
// Phase B (MLP, after proj):
//   x1   [65536,131072): f32 [64 tok][1024B], swz SW(tok) (over dead priv of waves 3..7)
//   ZN2  [0,32768)   : LN2 out fp16 (reuses ZN/O region)
//   H    [32768,65536): GELU out fp16 [64][512B] (over dead priv of waves 0..2)
#define X1_OFF 65536
#define MH_OFF 32768

__global__ __launch_bounds__(512, 2) void k_blk(
    const float* __restrict__ x, const _Float16* __restrict__ wsq,
    const _Float16* __restrict__ pwh, const float* __restrict__ qkvb,
    const float* __restrict__ g1, const float* __restrict__ b1,
    const float* __restrict__ temp, const float* __restrict__ btab,
    const float* __restrict__ amask, const float* __restrict__ pb,
    const float* __restrict__ g2, const float* __restrict__ b2,
    const _Float16* __restrict__ w1h, const float* __restrict__ fb1,
    const _Float16* __restrict__ w2h, const float* __restrict__ fb2,
    float* __restrict__ io) {
  __shared__ __align__(16) char smem[131072];
  const int tid = threadIdx.x;
  const int lane = tid & 63, w = tid >> 6;      // w = head index (0..7)
  const int lr = lane & 15, lk = lane >> 4;
  const int win = blockIdx.x;
  const int bb = win >> 6, wimg = win & 63;
  const int hb = wimg >> 3, wb = wimg & 7;
  const float scale = expf(temp[0]);
  char* const pwv = smem + 32768 + w * 12288;   // wave-private scratch (phase A)

  // --- LN1 at shifted source coords (roll(-3)) -> ZN fp16 ---
  {
    const float4 gz = ((const float4*)g1)[lane];
    const float4 bz = ((const float4*)b1)[lane];
    for (int n = w; n < 49; n += 8) {
      int i = n / 7, j = n - 7 * i;
      int rs = hb * 7 + i + 3; if (rs >= 56) rs -= 56;
      int cs = wb * 7 + j + 3; if (cs >= 56) cs -= 56;
      const float4 p = ((const float4*)(x + ((size_t)bb * 3136 + rs * 56 + cs) * 256))[lane];
      float mean = wsum(p.x + p.y + p.z + p.w) * (1.f / 256.f);
      float d0 = p.x - mean, d1 = p.y - mean, d2 = p.z - mean, d3 = p.w - mean;
      float var = wsum(d0 * d0 + d1 * d1 + d2 * d2 + d3 * d3) * (1.f / 256.f);
      float rstd = rsqrtf(var + 1e-6f);
      h4 z;
      z[0] = (_Float16)(d0 * rstd * gz.x + bz.x);
      z[1] = (_Float16)(d1 * rstd * gz.y + bz.y);
      z[2] = (_Float16)(d2 * rstd * gz.z + bz.z);
      z[3] = (_Float16)(d3 * rstd * gz.w + bz.w);
      *(h4*)(smem + ((n * 512 + lane * 8) ^ ((n & 7) << 4))) = z;
    }
  }
  __syncthreads();   // barrier 1: ZN ready

  // ---- qkv for head w: (64x256)@(256x96), 192 MFMA ----
  {
    f32x4 zz = {0.f, 0.f, 0.f, 0.f};
    f32x4 acc[4][6];
    #pragma unroll
    for (int t = 0; t < 4; ++t)
      #pragma unroll
      for (int c = 0; c < 6; ++c) acc[t][c] = zz;
    const _Float16* wr[6];
    #pragma unroll
    for (int c = 0; c < 6; ++c)
      wr[c] = wsq + ((size_t)(w * 96 + c * 16 + lr) * 256 + lk * 8);
    const int swzA = (lr & 7) << 4;
    #pragma unroll
    for (int ks = 0; ks < 8; ++ks) {
      const int ko = ks * 64 + lk * 16;
      h8 a[4];
      #pragma unroll
      for (int t = 0; t < 4; ++t)
        a[t] = *(const h8*)(smem + (((t * 16 + lr) * 512 + ko) ^ swzA));
      h8 b[6];
      #pragma unroll
      for (int c = 0; c < 6; ++c) b[c] = *(const h8*)(wr[c] + ks * 32);
      #pragma unroll
      for (int t = 0; t < 4; ++t)
        #pragma unroll
        for (int c = 0; c < 6; ++c) acc[t][c] = MFMA16(a[t], b[c], acc[t][c]);
    }
    // D -> Q/K/V (pad tokens >=49 written as 0)
    #pragma unroll
    for (int c = 0; c < 6; ++c) {
      const int mat = c >> 1;
      const int cc = (c & 1) * 16 + lr;
      const float bias = qkvb[mat * 256 + w * 32 + cc];
      #pragma unroll
      for (int t = 0; t < 4; ++t) {
        const int tok0 = t * 16 + lk * 4;
        if (mat == 2) {
          h4 pk;
          #pragma unroll
          for (int r = 0; r < 4; ++r) {
            float v = (tok0 + r < 49) ? (acc[t][c][r] + bias) : 0.f;
            pk[r] = (_Float16)v;
          }
          *(h4*)(pwv + 8192 + (tok0 >> 3) * 512 + cc * 16 + (tok0 & 7) * 2) = pk;
        } else {
          char* base = pwv + (mat ? 4096 : 0);
          const float mult = mat ? 1.f : scale;   // fold exp(temperature) into q
          #pragma unroll
          for (int r = 0; r < 4; ++r) {
            const int tok = tok0 + r;
            float v = (tok < 49) ? (acc[t][c][r] + bias) * mult : 0.f;
            *(_Float16*)(base + ((tok * 64 + cc * 2) ^ (((tok >> 1) & 3) << 4))) = (_Float16)v;
          }
        }
      }
    }
  }
  __syncthreads();   // barrier 2: all ZN reads done -> O may overlay ZN

  // ---- scores (16 MFMA) + in-register softmax -> P (overlays Q/K) ----
  {
    f32x4 zz = {0.f, 0.f, 0.f, 0.f};
    f32x4 s[4][4];
    #pragma unroll
    for (int t = 0; t < 4; ++t)
      #pragma unroll
      for (int m = 0; m < 4; ++m) s[t][m] = zz;
    const int swzq = ((lr >> 1) & 3) << 4;
    h8 aq[4], bk[4];
    #pragma unroll
    for (int t = 0; t < 4; ++t) {
      aq[t] = *(const h8*)(pwv + (((t * 16 + lr) * 64 + lk * 16) ^ swzq));
      bk[t] = *(const h8*)(pwv + 4096 + (((t * 16 + lr) * 64 + lk * 16) ^ swzq));
    }
    #pragma unroll
    for (int t = 0; t < 4; ++t)
      #pragma unroll
      for (int m = 0; m < 4; ++m) s[t][m] = MFMA16(aq[t], bk[m], s[t][m]);

    // diag(-1e30 pre-bias, per ref) + rel-pos bias + shift mask; cols>=49 -> -inf; rows>=49 -> 0
    const float* bt = btab + (size_t)w * 2401;
    const float* am = amask + (size_t)wimg * 2401;
    #pragma unroll
    for (int t = 0; t < 4; ++t) {
      #pragma unroll
      for (int r = 0; r < 4; ++r) {
        const int n = t * 16 + lk * 4 + r;
        if (n < 49) {
          #pragma unroll
          for (int m = 0; m < 4; ++m) {
            const int mm = m * 16 + lr;
            float sv;
            if (mm >= 49) sv = -1e38f;
            else {
              sv = s[t][m][r];
              if (mm == n) sv = -1e30f;
              const int ee = n * 49 + mm;
              sv += bt[ee] + am[ee];
            }
            s[t][m][r] = sv;
          }
        } else {
          #pragma unroll
          for (int m = 0; m < 4; ++m) s[t][m][r] = 0.f;   // finite garbage row, never stored
        }
      }
    }
    // softmax: row n lives on the 16 lanes sharing lk -> shfl_xor {1,2,4,8}
    #pragma unroll
    for (int t = 0; t < 4; ++t) {
      #pragma unroll
      for (int r = 0; r < 4; ++r) {
        float mx = fmaxf(fmaxf(s[t][0][r], s[t][1][r]), fmaxf(s[t][2][r], s[t][3][r]));
        mx = fmaxf(mx, __shfl_xor(mx, 1));
        mx = fmaxf(mx, __shfl_xor(mx, 2));
        mx = fmaxf(mx, __shfl_xor(mx, 4));
        mx = fmaxf(mx, __shfl_xor(mx, 8));
        float e0 = expf(s[t][0][r] - mx), e1 = expf(s[t][1][r] - mx);
        float e2 = expf(s[t][2][r] - mx), e3 = expf(s[t][3][r] - mx);
        float sm = e0 + e1 + e2 + e3;
        sm += __shfl_xor(sm, 1);
        sm += __shfl_xor(sm, 2);
        sm += __shfl_xor(sm, 4);
        sm += __shfl_xor(sm, 8);
        const float inv = 1.f / sm;
        const int n = t * 16 + lk * 4 + r;
        const int sw = (n & 7) << 4;
        char* pr = pwv + n * 128;
        *(_Float16*)(pr + ((lr * 2) ^ sw))          = (_Float16)(e0 * inv);
        *(_Float16*)(pr + (((16 + lr) * 2) ^ sw))   = (_Float16)(e1 * inv);
        *(_Float16*)(pr + (((32 + lr) * 2) ^ sw))   = (_Float16)(e2 * inv);
        *(_Float16*)(pr + (((48 + lr) * 2) ^ sw))   = (_Float16)(e3 * inv);
      }
    }
  }

  // ---- PV (16 MFMA) -> O slice (ch w*32..w*32+32) into shared O (ZN region) ----
  {
    f32x4 zz = {0.f, 0.f, 0.f, 0.f};
    f32x4 o0[4], o1[4];
    #pragma unroll
    for (int t = 0; t < 4; ++t) { o0[t] = zz; o1[t] = zz; }
    const int swzp = (lr & 7) << 4;
    #pragma unroll
    for (int ks = 0; ks < 2; ++ks) {
      h8 bv0 = *(const h8*)(pwv + 8192 + (ks * 4 + lk) * 512 + lr * 16);
      h8 bv1 = *(const h8*)(pwv + 8192 + (ks * 4 + lk) * 512 + (16 + lr) * 16);
      #pragma unroll
      for (int t = 0; t < 4; ++t) {
        h8 ap = *(const h8*)(pwv + (((t * 16 + lr) * 128 + ks * 64 + lk * 16) ^ swzp));
        o0[t] = MFMA16(ap, bv0, o0[t]);
        o1[t] = MFMA16(ap, bv1, o1[t]);
      }
    }
    #pragma unroll
    for (int t = 0; t < 4; ++t) {
      #pragma unroll
      for (int r = 0; r < 4; ++r) {
        const int tok = t * 16 + lk * 4 + r;
        const int sw = (tok & 7) << 4;
        char* orow = smem + tok * 512;
        *(_Float16*)(orow + (((w * 32 + lr) * 2) ^ sw))      = (_Float16)o0[t][r];
        *(_Float16*)(orow + (((w * 32 + 16 + lr) * 2) ^ sw)) = (_Float16)o1[t][r];
      }
    }
  }
  __syncthreads();   // barrier 3: full O ready

  // ---- proj: out cols w*32 .. +32, K=256 (64 MFMA); x1 = x + attn + pb -> LDS ----
  {
    f32x4 zz = {0.f, 0.f, 0.f, 0.f};
    f32x4 oacc[4][2];
    #pragma unroll
    for (int t = 0; t < 4; ++t) { oacc[t][0] = zz; oacc[t][1] = zz; }
    const int swzA = (lr & 7) << 4;
    const _Float16* pwr = pwh + (size_t)(w * 32 + lr) * 256 + lk * 8;
    #pragma unroll
    for (int ks = 0; ks < 8; ++ks) {
      const int ko = ks * 64 + lk * 16;
      h8 b0 = *(const h8*)(pwr + ks * 32);
      h8 b1 = *(const h8*)(pwr + 16 * 256 + ks * 32);
      #pragma unroll
      for (int t = 0; t < 4; ++t) {
        h8 a = *(const h8*)(smem + (((t * 16 + lr) * 512 + ko) ^ swzA));
        oacc[t][0] = MFMA16(a, b0, oacc[t][0]);
        oacc[t][1] = MFMA16(a, b1, oacc[t][1]);
      }
    }
    const float pb0 = pb[w * 32 + lr];
    const float pb1 = pb[w * 32 + 16 + lr];
    #pragma unroll
    for (int t = 0; t < 4; ++t) {
      #pragma unroll
      for (int r = 0; r < 4; ++r) {
        const int tok = t * 16 + lk * 4 + r;
        float v0 = 0.f, v1 = 0.f;
        if (tok < 49) {
          const int i = tok / 7, j = tok - 7 * i;
          int rs = hb * 7 + i + 3; if (rs >= 56) rs -= 56;
          int cs = wb * 7 + j + 3; if (cs >= 56) cs -= 56;
          const size_t ro = ((size_t)bb * 3136 + rs * 56 + cs) * 256 + w * 32 + lr;
          v0 = x[ro]      + oacc[t][0][r] + pb0;
          v1 = x[ro + 16] + oacc[t][1][r] + pb1;
        }
        char* xr = smem + X1_OFF + tok * 1024;
        *(float*)(xr + (((w * 32 + lr) * 4)      ^ SW(tok))) = v0;
        *(float*)(xr + (((w * 32 + 16 + lr) * 4) ^ SW(tok))) = v1;
      }
    }
  }
  __syncthreads();   // barrier 4: x1 complete; priv regions dead -> ZN2/H may be written

  // ---- LN2 (reads x1 from LDS) -> ZN2 fp16 @0 ----
  {
    const float4 gz = ((const float4*)g2)[lane];
    const float4 bz = ((const float4*)b2)[lane];
    for (int n = w; n < 64; n += 8) {
      const float4 p = *(const float4*)(smem + X1_OFF + n * 1024 + ((lane * 16) ^ SW(n)));
      float mean = wsum(p.x + p.y + p.z + p.w) * (1.f / 256.f);
      float d0 = p.x - mean, d1 = p.y - mean, d2 = p.z - mean, d3 = p.w - mean;
      float var = wsum(d0 * d0 + d1 * d1 + d2 * d2 + d3 * d3) * (1.f / 256.f);
      float rstd = rsqrtf(var + 1e-6f);
      h4 z;
      z[0] = (_Float16)(d0 * rstd * gz.x + bz.x);
      z[1] = (_Float16)(d1 * rstd * gz.y + bz.y);
      z[2] = (_Float16)(d2 * rstd * gz.z + bz.z);
      z[3] = (_Float16)(d3 * rstd * gz.w + bz.w);
      *(h4*)(smem + ((n * 512 + lane * 8) ^ ((n & 7) << 4))) = z;
    }
  }
  __syncthreads();

  // ---- MLP: 4 chunks of 256 hidden; wave owns 32 cols per chunk ----
  f32x4 zzm = {0.f, 0.f, 0.f, 0.f};
  f32x4 macc[4][2];
  #pragma unroll
  for (int t = 0; t < 4; ++t) { macc[t][0] = zzm; macc[t][1] = zzm; }
  const int swz = (lr & 7) << 4;

  for (int ch = 0; ch < 4; ++ch) {
    f32x4 facc[4][2];
    #pragma unroll
    for (int t = 0; t < 4; ++t) { facc[t][0] = zzm; facc[t][1] = zzm; }
    {
      const _Float16* w1p = w1h + (size_t)(ch * 256 + w * 32 + lr) * 256 + lk * 8;
      #pragma unroll
      for (int ks = 0; ks < 8; ++ks) {
        const int ko = ks * 64 + lk * 16;
        h8 b0 = *(const h8*)(w1p + ks * 32);
        h8 b1 = *(const h8*)(w1p + 16 * 256 + ks * 32);
        #pragma unroll
        for (int t = 0; t < 4; ++t) {
          h8 a = *(const h8*)(smem + (((t * 16 + lr) * 512 + ko) ^ swz));
          facc[t][0] = MFMA16(a, b0, facc[t][0]);
          facc[t][1] = MFMA16(a, b1, facc[t][1]);
        }
      }
    }
    // GELU -> H fp16 (col = w*32 + nt*16 + lr -> byte w*64 + nt*32 + lr*2)
    #pragma unroll
    for (int nt = 0; nt < 2; ++nt) {
      const float bb2 = fb1[ch * 256 + w * 32 + nt * 16 + lr];
      #pragma unroll
      for (int t = 0; t < 4; ++t) {
        #pragma unroll
        for (int r = 0; r < 4; ++r) {
          float a = facc[t][nt][r] + bb2;
          float gl = 0.5f * a * (1.f + erff(a * 0.70710678118654752f));
          const int tok = t * 16 + lk * 4 + r;
          *(_Float16*)(smem + MH_OFF +
                       ((tok * 512 + w * 64 + nt * 32 + lr * 2) ^ ((tok & 7) << 4))) =
              (_Float16)gl;
        }
      }
    }
    __syncthreads();
    // fc2 accumulate
    {
      const _Float16* w2p = w2h + (size_t)(w * 32 + lr) * 1024 + ch * 256 + lk * 8;
      #pragma unroll
      for (int ks = 0; ks < 8; ++ks) {
        const int ko = ks * 64 + lk * 16;
        h8 b0 = *(const h8*)(w2p + ks * 32);
        h8 b1 = *(const h8*)(w2p + 16 * 1024 + ks * 32);
        #pragma unroll
        for (int t = 0; t < 4; ++t) {
          h8 a = *(const h8*)(smem + MH_OFF + (((t * 16 + lr) * 512 + ko) ^ swz));
          macc[t][0] = MFMA16(a, b0, macc[t][0]);
          macc[t][1] = MFMA16(a, b1, macc[t][1]);
        }
      }
    }
    __syncthreads();   // protect H before next chunk's GELU writes
  }

  // ---- accumulate mlp + fb2 into x1 (per-thread scalar RMW, swizzled) ----
  {
    const float bv0 = fb2[w * 32 + lr];
    const float bv1 = fb2[w * 32 + 16 + lr];
    #pragma unroll
    for (int t = 0; t < 4; ++t) {
      #pragma unroll
      for (int r = 0; r < 4; ++r) {
        const int tok = t * 16 + lk * 4 + r;
        char* xr = smem + X1_OFF + tok * 1024;
        float* p0 = (float*)(xr + (((w * 32 + lr) * 4)      ^ SW(tok)));
        float* p1 = (float*)(xr + (((w * 32 + 16 + lr) * 4) ^ SW(tok)));
        *p0 += macc[t][0][r] + bv0;
        *p1 += macc[t][1][r] + bv1;
      }
    }
  }
  __syncthreads();

  // ---- final coalesced store: out row = x1 row (already includes everything) ----
  for (int n = w; n < 49; n += 8) {
    const int i = n / 7, j = n - 7 * i;
    int rs = hb * 7 + i + 3; if (rs >= 56) rs -= 56;
    int cs = wb * 7 + j + 3; if (cs >= 56) cs -= 56;
    const float4 v = *(const float4*)(smem + X1_OFF + n * 1024 + ((lane * 16) ^ SW(n)));
    *(float4*)(io + ((size_t)bb * 3136 + rs * 56 + cs) * 256 + lane * 4) = v;
  }
}

extern "C" void kernel_launch(void* const* d_in, const int* in_sizes, int n_in,
                              void* d_out, int out_size, void* d_ws, size_t ws_size,
                              hipStream_t stream) {
  const float* x     = (const float*)d_in[0];
  const float* amask = (const float*)d_in[1];
  const float* g1    = (const float*)d_in[2];
  const float* b1    = (const float*)d_in[3];
  const float* qkvw  = (const float*)d_in[4];
  const float* qkvb  = (const float*)d_in[5];
  const float* temp  = (const float*)d_in[6];
  const float* rtab  = (const float*)d_in[7];
  const float* pw    = (const float*)d_in[8];
  const float* pb    = (const float*)d_in[9];
  const float* g2    = (const float*)d_in[10];
  const float* b2    = (const float*)d_in[11];
  const float* w1    = (const float*)d_in[12];
  const float* fb1   = (const float*)d_in[13];
  const float* w2    = (const float*)d_in[14];
  const float* fb2   = (const float*)d_in[15];
  const int* rpi     = (const int*)d_in[16];
  // d_in[17], d_in[18] = H, W (fixed 56)

  char* ws = (char*)d_ws;
  _Float16* wsq = (_Float16*)ws;               // 393,216 B (768x256 fp16)
  _Float16* pwh = (_Float16*)(ws + 393216);    // 131,072 B (256x256 fp16)
  _Float16* w1h = (_Float16*)(ws + 524288);    //  524,288 B (1024x256 fp16)
  _Float16* w2h = (_Float16*)(ws + 1048576);   //  524,288 B (256x1024 fp16)
  float* btab   = (float*)(ws + 1572864);      //   76,832 B (8x2401 f32)
  float* io = (float*)d_out;

  k_prep_qkv<<<768, 256, 0, stream>>>(qkvw, wsq);
  k_prep_pw<<<256, 256, 0, stream>>>(pw, pwh);
  k_prep_w1<<<1024, 256, 0, stream>>>(w1, w1h);
  k_prep_w2<<<1024, 256, 0, stream>>>(w2, w2h);
  k_prep_btab<<<10, 256, 0, stream>>>(rpi, rtab, btab);
  k_blk<<<2048, 512, 0, stream>>>(x, wsq, pwh, qkvb, g1, b1, temp, btab,
                                  amask, pb, g2, b2, w1h, fb1, w2h, fb2, io);
}